// Round 2
// 106.053 us; speedup vs baseline: 1.0127x; 1.0127x over previous
//
#include <hip/hip_runtime.h>
#include <stdint.h>

// Problem constants: B=32, N=1024, C=64, G=64
//
// R17 = R16 resubmission (round-1 bench died at container level with no
// kernel signal; design re-audited: uniform barriers, in-order vmcnt
// retirement proof holds under both compiler issue orders, DMA bounds ok).
//
// Two-pass restructure rationale (from R15 counters: 52us, MfmaUtil 6.7%,
// VALUBusy 19.6%, Occ 14.4%, HBM 2-7% -> latency/overhead-bound):
// the K-tile loop's "produce" phase (16 MFMA + 32 ds_write_u16 + ~24 f2h
// per wave per tile) is >=half the issue work and is 16x redundant across
// the 16 q-tile blocks of a batch.
//   Pass 1 (proj_kernel): compute Q/K/V once per 64-row tile with
//   BIT-IDENTICAL arithmetic to R15 (Q split-precision 6-MFMA, K/V hi-only
//   2-MFMA, same order) and store pre-swizzled fp16 "LDS images" in d_ws.
//   Pass 2 (attn_kernel): Q frags load global->VGPR directly; K/V tiles
//   arrive via global_load_lds DMA (4 issues/wave/tile) into a 3-deep
//   buffer with counted s_waitcnt vmcnt(4) + raw s_barrier (m201/m218
//   pattern: prefetches stay in flight across barriers). Consume phase is
//   verbatim R15 -> outputs bit-identical.
// Fallback: if ws_size < 12MB, launch the unmodified R15 kernel.

typedef __attribute__((ext_vector_type(4))) float    floatx4;
typedef __attribute__((ext_vector_type(8))) _Float16 halfx8;

static __device__ __forceinline__ unsigned short f2h(float f) {
    union { _Float16 h; unsigned short u; } v; v.h = (_Float16)f;
    return v.u;
}
static __device__ __forceinline__ float h2f(unsigned short u) {
    union { unsigned short u; _Float16 h; } v; v.u = u;
    return (float)v.h;
}

#define MFMA16(a, bb, c) __builtin_amdgcn_mfma_f32_16x16x32_f16((a), (bb), (c), 0, 0, 0)

#define GLD_LDS16(g, l) __builtin_amdgcn_global_load_lds(                  \
    (const __attribute__((address_space(1))) void*)(g),                    \
    (__attribute__((address_space(3))) void*)(l), 16, 0, 0)

// ============================================================================
// Pass 1: projections. Block blk handles x rows blk*64 .. blk*64+63
// (blk = b*16 + tile). Writes three 8KB pre-swizzled fp16 images per block:
//   Q/K image: img[row*64 + ((c8 ^ (row&7))*8) + j] = P[row][c8*8+j]
//   V image  : img[g*64  + ((kc8 ^ (g&7))*8) + j]   = V[kc8*8+j][g]   (V^T)
// ============================================================================
__global__ __launch_bounds__(256, 2) void proj_kernel(
    const float* __restrict__ x,
    const float* __restrict__ Wq, const float* __restrict__ bq,
    const float* __restrict__ Wk, const float* __restrict__ bk,
    const float* __restrict__ Wv, const float* __restrict__ bv,
    unsigned short* __restrict__ qimg,
    unsigned short* __restrict__ kimg,
    unsigned short* __restrict__ vimg)
{
    __shared__ __align__(16) unsigned short sm[24576];   // 48 KB
    const int XH = 0, XL = 4096, WQH = 8192, WQL = 12288, WKH = 16384, WVH = 20480;

    const int tid  = threadIdx.x;
    const int blk  = blockIdx.x;          // 0..511
    const int lane = tid & 63;
    const int w    = tid >> 6;
    const int l15  = lane & 15;
    const int quad = lane >> 4;
    const int rl   = lane >> 2;
    const int c8a  = 2 * (lane & 3);
    const int c8b  = c8a + 1;
    const int sidx_a = rl * 64 + ((c8a ^ (rl & 7)) * 8);
    const int sidx_b = rl * 64 + ((c8b ^ (rl & 7)) * 8);

    // ---- stage x (hi + lo residual), wave-private 16-row slices ----
    {
        const float* xrow = x + (size_t)(blk * 64 + w * 16) * 64;
#pragma unroll
        for (int i = 0; i < 2; ++i) {
            int c8   = (i == 0) ? c8a : c8b;
            int sidx = (i == 0) ? sidx_a : sidx_b;
            const float4* gp = (const float4*)(xrow + rl * 64 + c8 * 8);
            float4 f0 = gp[0], f1 = gp[1];
            float fv[8] = { f0.x, f0.y, f0.z, f0.w, f1.x, f1.y, f1.z, f1.w };
            __align__(16) unsigned short thi[8], tlo[8];
#pragma unroll
            for (int j = 0; j < 8; ++j) {
                unsigned short hi = f2h(fv[j]);
                thi[j] = hi;
                tlo[j] = f2h(fv[j] - h2f(hi));
            }
            *(uint4*)&sm[XH + w * 1024 + sidx] = *(uint4*)thi;
            *(uint4*)&sm[XL + w * 1024 + sidx] = *(uint4*)tlo;
        }
    }
    // ---- stage Wq(hi,lo), Wk, Wv  ([g][c] transposed, XOR-swizzled) ----
    {
        int g = tid & 63, ci = tid >> 6;
#pragma unroll
        for (int j = 0; j < 16; ++j) {
            int c = ci * 16 + j;
            int idx = g * 64 + (((c >> 3) ^ (g & 7)) * 8) + (c & 7);
            float fq = Wq[c * 64 + g];
            unsigned short qhi = f2h(fq);
            sm[WQH + idx] = qhi;
            sm[WQL + idx] = f2h(fq - h2f(qhi));
            sm[WKH + idx] = f2h(Wk[c * 64 + g]);
            sm[WVH + idx] = f2h(Wv[c * 64 + g]);
        }
    }
    __syncthreads();

    const int fidx0 = l15 * 64 + (((0 + quad) ^ (l15 & 7)) * 8);
    const int fidx1 = l15 * 64 + (((4 + quad) ^ (l15 & 7)) * 8);
    halfx8 ah0 = *(const halfx8*)&sm[XH + w * 1024 + fidx0];
    halfx8 ah1 = *(const halfx8*)&sm[XH + w * 1024 + fidx1];
    halfx8 al0 = *(const halfx8*)&sm[XL + w * 1024 + fidx0];
    halfx8 al1 = *(const halfx8*)&sm[XL + w * 1024 + fidx1];

    floatx4 vacc[4];
#pragma unroll
    for (int gs = 0; gs < 4; ++gs) {
        int brow = gs * 16 + l15;
        int b0 = brow * 64 + (((0 + quad) ^ (brow & 7)) * 8);
        int b1 = brow * 64 + (((4 + quad) ^ (brow & 7)) * 8);
        halfx8 bh0 = *(const halfx8*)&sm[WQH + b0];
        halfx8 bh1 = *(const halfx8*)&sm[WQH + b1];
        halfx8 bl0 = *(const halfx8*)&sm[WQL + b0];
        halfx8 bl1 = *(const halfx8*)&sm[WQL + b1];
        halfx8 wk0 = *(const halfx8*)&sm[WKH + b0];
        halfx8 wk1 = *(const halfx8*)&sm[WKH + b1];
        halfx8 wv0 = *(const halfx8*)&sm[WVH + b0];
        halfx8 wv1 = *(const halfx8*)&sm[WVH + b1];

        float bbq = bq[gs * 16 + l15];
        floatx4 qa = { bbq, bbq, bbq, bbq };
        qa = MFMA16(ah0, bh0, qa);
        qa = MFMA16(ah1, bh1, qa);
        qa = MFMA16(ah0, bl0, qa);
        qa = MFMA16(ah1, bl1, qa);
        qa = MFMA16(al0, bh0, qa);
        qa = MFMA16(al1, bh1, qa);

        float bbk = bk[gs * 16 + l15];
        float bbv = bv[gs * 16 + l15];
        floatx4 ka = { bbk, bbk, bbk, bbk };
        floatx4 va = { bbv, bbv, bbv, bbv };
        ka = MFMA16(ah0, wk0, ka);
        ka = MFMA16(ah1, wk1, ka);
        va = MFMA16(ah0, wv0, va);
        va = MFMA16(ah1, wv1, va);
        vacc[gs] = va;

        // Q image -> XH (own-wave rows), K image -> XL (own-wave rows).
        // ah/al frags already in regs, so overwriting our slice is safe.
        int c8 = gs * 2 + (l15 >> 3);
#pragma unroll
        for (int r = 0; r < 4; ++r) {
            int row = w * 16 + quad * 4 + r;
            int idx = row * 64 + ((c8 ^ (row & 7)) * 8) + (l15 & 7);
            sm[XH + idx] = f2h(qa[r]);
            sm[XL + idx] = f2h(ka[r]);
        }
    }
    __syncthreads();   // all waves done reading Wq-hi -> WQH reusable as V image
#pragma unroll
    for (int gs = 0; gs < 4; ++gs) {
        int g = gs * 16 + l15;
#pragma unroll
        for (int r = 0; r < 4; ++r) {
            int key = w * 16 + quad * 4 + r;
            sm[WQH + g * 64 + (((key >> 3) ^ (g & 7)) * 8) + (key & 7)] = f2h(vacc[gs][r]);
        }
    }
    __syncthreads();

    // ---- cooperative copy: 3 x 8KB images -> global workspace ----
    {
        const size_t tb = (size_t)blk * 4096;   // shorts per image
#pragma unroll
        for (int i = 0; i < 2; ++i) {
            int ci = i * 256 + tid;             // 512 x 16B chunks per image
            *(uint4*)&qimg[tb + ci * 8] = *(const uint4*)&sm[XH  + ci * 8];
            *(uint4*)&kimg[tb + ci * 8] = *(const uint4*)&sm[XL  + ci * 8];
            *(uint4*)&vimg[tb + ci * 8] = *(const uint4*)&sm[WQH + ci * 8];
        }
    }
}

// ============================================================================
// Pass 2: attention. LDS = KL[3] + VS[3] (8KB tiles) + PS (per-wave P
// staging) = 56KB. One raw barrier per tile; K/V DMA'd 2 tiles ahead.
// ============================================================================
__global__ __launch_bounds__(256, 2) void attn_kernel(
    const unsigned short* __restrict__ qimg,
    const unsigned short* __restrict__ kimg,
    const unsigned short* __restrict__ vimg,
    const int* __restrict__ valid_len, float* __restrict__ out)
{
    __shared__ __align__(16) unsigned short smem[28672];  // 56 KB
    __shared__ int sched[32];
    const int VSB = 12288, PS_OFF = 24576;

    const int tid  = threadIdx.x;
    const int blk  = blockIdx.x;          // 0..511
    const int lane = tid & 63;
    const int w    = tid >> 6;
    const int l15  = lane & 15;
    const int quad = lane >> 4;

    // ---------- device-side balanced schedule (identical in every block) ----
    if (tid < 32) {
        int vlb = valid_len[tid];
        int ntb = (vlb == 0) ? 16 : ((vlb + 63) >> 6);
        int rank = 0;
        for (int b2 = 0; b2 < 32; ++b2) {
            int vl2 = valid_len[b2];
            int nt2 = (vl2 == 0) ? 16 : ((vl2 + 63) >> 6);
            rank += (nt2 > ntb) || (nt2 == ntb && b2 < tid);
        }
        sched[rank] = tid;
    }
    __syncthreads();

    const int b    = (blk < 256) ? sched[blk >> 4] : sched[31 - ((blk - 256) >> 4)];
    const int qt   = blk & 15;
    const int row0 = b * 1024 + qt * 64;

    const int vl    = valid_len[b];
    const int nt    = (vl == 0) ? 16 : ((vl + 63) >> 6);
    const int fullt = vl >> 6;

    // ---- Q fragments straight from the global image (no LDS) ----
    const int arow = w * 16 + l15;
    const unsigned short* qb = qimg + (size_t)(b * 16 + qt) * 4096;
    halfx8 aq0 = *(const halfx8*)&qb[arow * 64 + (((0 + quad) ^ (arow & 7)) * 8)];
    halfx8 aq1 = *(const halfx8*)&qb[arow * 64 + (((4 + quad) ^ (arow & 7)) * 8)];

    // ---- per-wave DMA bases: wave w stages bytes [w*2048, w*2048+2047] ----
    const char* kbase = (const char*)kimg + (size_t)b * 131072 + w * 2048 + lane * 16;
    const char* vbase = (const char*)vimg + (size_t)b * 131072 + w * 2048 + lane * 16;

    // prologue prefetch: tiles 0 and 1 (4 issues/wave/tile)
    {
        unsigned short* kd = &smem[w * 1024];
        unsigned short* vd = &smem[VSB + w * 1024];
        GLD_LDS16(kbase,        kd);
        GLD_LDS16(kbase + 1024, kd + 512);
        GLD_LDS16(vbase,        vd);
        GLD_LDS16(vbase + 1024, vd + 512);
        if (nt > 1) {
            unsigned short* kd1 = &smem[4096 + w * 1024];
            unsigned short* vd1 = &smem[VSB + 4096 + w * 1024];
            GLD_LDS16(kbase + 8192,        kd1);
            GLD_LDS16(kbase + 8192 + 1024, kd1 + 512);
            GLD_LDS16(vbase + 8192,        vd1);
            GLD_LDS16(vbase + 8192 + 1024, vd1 + 512);
        }
    }

    float m_r[4]    = { -INFINITY, -INFINITY, -INFINITY, -INFINITY };
    float l_lane[4] = { 0.f, 0.f, 0.f, 0.f };
    floatx4 o[4] = { {0,0,0,0}, {0,0,0,0}, {0,0,0,0}, {0,0,0,0} };

    int cur = 0;
    for (int t = 0; t < nt; ++t) {
        // retire THIS wave's 4 loads for tile t (t+1's stay in flight),
        // then barrier so every wave's portion of tile t is in LDS.
        if (t + 1 < nt) asm volatile("s_waitcnt vmcnt(4)" ::: "memory");
        else            asm volatile("s_waitcnt vmcnt(0)" ::: "memory");
        __builtin_amdgcn_s_barrier();
        asm volatile("" ::: "memory");

        // issue tile t+2 into buf (t+2)%3 (last consumed at t-1, one barrier ago)
        if (t + 2 < nt) {
            int nb = cur + 2; if (nb >= 3) nb -= 3;
            unsigned short* kd = &smem[nb * 4096 + w * 1024];
            unsigned short* vd = &smem[VSB + nb * 4096 + w * 1024];
            const char* kt2 = kbase + (size_t)(t + 2) * 8192;
            const char* vt2 = vbase + (size_t)(t + 2) * 8192;
            GLD_LDS16(kt2,        kd);
            GLD_LDS16(kt2 + 1024, kd + 512);
            GLD_LDS16(vt2,        vd);
            GLD_LDS16(vt2 + 1024, vd + 512);
        }

        const int KLc = cur * 4096;
        const int VSc = VSB + cur * 4096;

        // ---- scores ----
        floatx4 s[4];
#pragma unroll
        for (int sub = 0; sub < 4; ++sub) {
            int krow = sub * 16 + l15;
            halfx8 bk0 = *(const halfx8*)&smem[KLc + krow * 64 + (((0 + quad) ^ (krow & 7)) * 8)];
            halfx8 bk1 = *(const halfx8*)&smem[KLc + krow * 64 + (((4 + quad) ^ (krow & 7)) * 8)];
            floatx4 acc = { 0, 0, 0, 0 };
            acc = MFMA16(aq0, bk0, acc);
            acc = MFMA16(aq1, bk1, acc);
            s[sub] = acc;
        }
        if (t >= fullt) {
#pragma unroll
            for (int sub = 0; sub < 4; ++sub) {
                int key = t * 64 + sub * 16 + l15;
                if (key >= vl) { s[sub][0] = -1e6f; s[sub][1] = -1e6f; s[sub][2] = -1e6f; s[sub][3] = -1e6f; }
            }
        }

        // ---- online softmax (verbatim R15) ----
        float p[4][4];
        float alpha[4];
#pragma unroll
        for (int r = 0; r < 4; ++r) {
            float mx = fmaxf(fmaxf(s[0][r], s[1][r]), fmaxf(s[2][r], s[3][r]));
#pragma unroll
            for (int off = 1; off < 16; off <<= 1)
                mx = fmaxf(mx, __shfl_xor(mx, off, 64));
            float mnew = fmaxf(m_r[r], mx);
            alpha[r] = __expf(m_r[r] - mnew);
            float psum = 0.f;
#pragma unroll
            for (int sub = 0; sub < 4; ++sub) {
                float pv = __expf(s[sub][r] - mnew);
                p[sub][r] = pv;
                psum += pv;
            }
            l_lane[r] = l_lane[r] * alpha[r] + psum;
            m_r[r] = mnew;
        }
#pragma unroll
        for (int gs = 0; gs < 4; ++gs) {
            o[gs][0] *= alpha[0]; o[gs][1] *= alpha[1];
            o[gs][2] *= alpha[2]; o[gs][3] *= alpha[3];
        }

        // ---- P staging (wave-private) + PV ----
        unsigned short* psw = &smem[PS_OFF + w * 1024];
#pragma unroll
        for (int sub = 0; sub < 4; ++sub) {
            int c8 = sub * 2 + (l15 >> 3);
#pragma unroll
            for (int r = 0; r < 4; ++r) {
                int row = quad * 4 + r;
                psw[row * 64 + ((c8 ^ (row & 7)) * 8) + (l15 & 7)] = f2h(p[sub][r]);
            }
        }
        halfx8 ap0 = *(const halfx8*)&psw[l15 * 64 + (((0 + quad) ^ (l15 & 7)) * 8)];
        halfx8 ap1 = *(const halfx8*)&psw[l15 * 64 + (((4 + quad) ^ (l15 & 7)) * 8)];

#pragma unroll
        for (int gs = 0; gs < 4; ++gs) {
            int grow = gs * 16 + l15;
            halfx8 bv0 = *(const halfx8*)&smem[VSc + grow * 64 + (((0 + quad) ^ (grow & 7)) * 8)];
            halfx8 bv1 = *(const halfx8*)&smem[VSc + grow * 64 + (((4 + quad) ^ (grow & 7)) * 8)];
            o[gs] = MFMA16(ap0, bv0, o[gs]);
            o[gs] = MFMA16(ap1, bv1, o[gs]);
        }

        cur = (cur == 2) ? 0 : cur + 1;
    }

    // ---- final 16-lane sum butterfly, store ----
    float l[4];
#pragma unroll
    for (int r = 0; r < 4; ++r) {
        float ss = l_lane[r];
#pragma unroll
        for (int off = 1; off < 16; off <<= 1)
            ss += __shfl_xor(ss, off, 64);
        l[r] = ss;
    }
#pragma unroll
    for (int gs = 0; gs < 4; ++gs) {
#pragma unroll
        for (int r = 0; r < 4; ++r) {
            int row = row0 + w * 16 + quad * 4 + r;
            out[row * 64 + gs * 16 + l15] = o[gs][r] / l[r];
        }
    }
}

// ============================================================================
// Fallback: unmodified R15 single-pass kernel (used if ws_size < 12 MB)
// ============================================================================
__global__ __launch_bounds__(256, 2) void fused_attn_fallback(
    const float* __restrict__ x,
    const float* __restrict__ Wq, const float* __restrict__ bq,
    const float* __restrict__ Wk, const float* __restrict__ bk,
    const float* __restrict__ Wv, const float* __restrict__ bv,
    const int* __restrict__ valid_len, float* __restrict__ out)
{
    __shared__ __align__(16) unsigned short smem[28672];   // 56 KB
    __shared__ int sched[32];

    const int Q_OFF = 0, XH_OFF = 4096, KL0_OFF = 8192, KL1_OFF = 12288,
              VS0_OFF = 16384, VS1_OFF = 20480, PS_OFF = 24576;

    const int tid  = threadIdx.x;
    const int blk  = blockIdx.x;
    const int lane = tid & 63;
    const int w    = tid >> 6;
    const int l15  = lane & 15;
    const int quad = lane >> 4;

    if (tid < 32) {
        int vlb = valid_len[tid];
        int ntb = (vlb == 0) ? 16 : ((vlb + 63) >> 6);
        int rank = 0;
        for (int b2 = 0; b2 < 32; ++b2) {
            int vl2 = valid_len[b2];
            int nt2 = (vl2 == 0) ? 16 : ((vl2 + 63) >> 6);
            rank += (nt2 > ntb) || (nt2 == ntb && b2 < tid);
        }
        sched[rank] = tid;
    }
    __syncthreads();

    const int hv   = (blk < 256);
    const int b    = hv ? sched[blk >> 4] : sched[31 - ((blk - 256) >> 4)];
    const int n0   = (blk & 15) * 64;
    const int row0 = b * 1024 + n0;

    const int xsl  = XH_OFF + w * 1024;
    const int fidx0 = l15 * 64 + (((0 + quad) ^ (l15 & 7)) * 8);
    const int fidx1 = l15 * 64 + (((4 + quad) ^ (l15 & 7)) * 8);
    const int rl   = lane >> 2;
    const int c8a  = 2 * (lane & 3);
    const int c8b  = 2 * (lane & 3) + 1;
    const int sidx_a = rl * 64 + ((c8a ^ (rl & 7)) * 8);
    const int sidx_b = rl * 64 + ((c8b ^ (rl & 7)) * 8);

    const int vl    = valid_len[b];
    const int nt    = (vl == 0) ? 16 : ((vl + 63) >> 6);
    const int fullt = vl >> 6;

    {
        const float* xrow = x + (size_t)(row0 + w * 16) * 64;
#pragma unroll
        for (int i = 0; i < 2; ++i) {
            int c8 = (i == 0) ? c8a : c8b;
            int sidx = (i == 0) ? sidx_a : sidx_b;
            const float4* gp = (const float4*)(xrow + rl * 64 + c8 * 8);
            float4 f0 = gp[0], f1 = gp[1];
            float fv[8] = { f0.x, f0.y, f0.z, f0.w, f1.x, f1.y, f1.z, f1.w };
            __align__(16) unsigned short thi[8], tlo[8];
#pragma unroll
            for (int j = 0; j < 8; ++j) {
                unsigned short hi = f2h(fv[j]);
                thi[j] = hi;
                tlo[j] = f2h(fv[j] - h2f(hi));
            }
            *(uint4*)&smem[xsl + sidx]                = *(uint4*)thi;
            *(uint4*)&smem[VS0_OFF + w * 1024 + sidx] = *(uint4*)tlo;
        }
    }
    {
        int g = tid & 63, ci = tid >> 6;
#pragma unroll
        for (int j = 0; j < 16; ++j) {
            int c = ci * 16 + j;
            int idx = g * 64 + (((c >> 3) ^ (g & 7)) * 8) + (c & 7);
            float fq = Wq[c * 64 + g];
            unsigned short qhi = f2h(fq);
            smem[KL0_OFF + idx] = qhi;
            smem[KL1_OFF + idx] = f2h(fq - h2f(qhi));
            smem[VS1_OFF + idx] = f2h(Wk[c * 64 + g]);
            smem[PS_OFF  + idx] = f2h(Wv[c * 64 + g]);
        }
    }
    __syncthreads();

    halfx8 wkf0[4], wkf1[4], wvf0[4], wvf1[4];
#pragma unroll
    for (int gs = 0; gs < 4; ++gs) {
        int brow = gs * 16 + l15;
        int b0 = brow * 64 + (((0 + quad) ^ (brow & 7)) * 8);
        int b1 = brow * 64 + (((4 + quad) ^ (brow & 7)) * 8);
        wkf0[gs] = *(const halfx8*)&smem[VS1_OFF + b0];
        wkf1[gs] = *(const halfx8*)&smem[VS1_OFF + b1];
        wvf0[gs] = *(const halfx8*)&smem[PS_OFF + b0];
        wvf1[gs] = *(const halfx8*)&smem[PS_OFF + b1];
    }

    {
        halfx8 ah0 = *(const halfx8*)&smem[xsl + fidx0];
        halfx8 ah1 = *(const halfx8*)&smem[xsl + fidx1];
        halfx8 al0 = *(const halfx8*)&smem[VS0_OFF + w * 1024 + fidx0];
        halfx8 al1 = *(const halfx8*)&smem[VS0_OFF + w * 1024 + fidx1];
#pragma unroll
        for (int gs = 0; gs < 4; ++gs) {
            int brow = gs * 16 + l15;
            float bb = bq[gs * 16 + l15];
            floatx4 acc = { bb, bb, bb, bb };
            int b0 = brow * 64 + (((0 + quad) ^ (brow & 7)) * 8);
            int b1 = brow * 64 + (((4 + quad) ^ (brow & 7)) * 8);
            halfx8 bh0 = *(const halfx8*)&smem[KL0_OFF + b0];
            halfx8 bh1 = *(const halfx8*)&smem[KL0_OFF + b1];
            halfx8 bl0 = *(const halfx8*)&smem[KL1_OFF + b0];
            halfx8 bl1 = *(const halfx8*)&smem[KL1_OFF + b1];
            acc = MFMA16(ah0, bh0, acc);
            acc = MFMA16(ah1, bh1, acc);
            acc = MFMA16(ah0, bl0, acc);
            acc = MFMA16(ah1, bl1, acc);
            acc = MFMA16(al0, bh0, acc);
            acc = MFMA16(al1, bh1, acc);
            int c8 = gs * 2 + (l15 >> 3);
#pragma unroll
            for (int r = 0; r < 4; ++r) {
                int row = w * 16 + quad * 4 + r;
                smem[Q_OFF + row * 64 + ((c8 ^ (row & 7)) * 8) + (l15 & 7)] = f2h(acc[r]);
            }
        }
    }
    const int arow = w * 16 + l15;
    halfx8 aq0 = *(const halfx8*)&smem[Q_OFF + arow * 64 + (((0 + quad) ^ (arow & 7)) * 8)];
    halfx8 aq1 = *(const halfx8*)&smem[Q_OFF + arow * 64 + (((4 + quad) ^ (arow & 7)) * 8)];

    {
        const float* xrow = x + (size_t)(b * 1024 + w * 16) * 64;
#pragma unroll
        for (int i = 0; i < 2; ++i) {
            int c8 = (i == 0) ? c8a : c8b;
            int sidx = (i == 0) ? sidx_a : sidx_b;
            const float4* gp = (const float4*)(xrow + rl * 64 + c8 * 8);
            float4 f0 = gp[0], f1 = gp[1];
            __align__(16) unsigned short thi[8] = {
                f2h(f0.x), f2h(f0.y), f2h(f0.z), f2h(f0.w),
                f2h(f1.x), f2h(f1.y), f2h(f1.z), f2h(f1.w) };
            *(uint4*)&smem[xsl + sidx] = *(uint4*)thi;
        }
    }
    __syncthreads();

    {
        halfx8 kxh0 = *(const halfx8*)&smem[xsl + fidx0];
        halfx8 kxh1 = *(const halfx8*)&smem[xsl + fidx1];
#pragma unroll
        for (int gs = 0; gs < 4; ++gs) {
            float bbk = bk[gs * 16 + l15];
            float bbv = bv[gs * 16 + l15];
            floatx4 kacc = { bbk, bbk, bbk, bbk };
            floatx4 vacc = { bbv, bbv, bbv, bbv };
            kacc = MFMA16(kxh0, wkf0[gs], kacc);
            kacc = MFMA16(kxh1, wkf1[gs], kacc);
            vacc = MFMA16(kxh0, wvf0[gs], vacc);
            vacc = MFMA16(kxh1, wvf1[gs], vacc);
            int c8 = gs * 2 + (l15 >> 3);
            int g  = gs * 16 + l15;
#pragma unroll
            for (int r = 0; r < 4; ++r) {
                int key = w * 16 + quad * 4 + r;
                smem[KL0_OFF + key * 64 + ((c8 ^ (key & 7)) * 8) + (l15 & 7)] = f2h(kacc[r]);
                smem[VS0_OFF + g * 64 + (((key >> 3) ^ (g & 7)) * 8) + (key & 7)] = f2h(vacc[r]);
            }
        }
    }

    float m_r[4]    = { -INFINITY, -INFINITY, -INFINITY, -INFINITY };
    float l_lane[4] = { 0.f, 0.f, 0.f, 0.f };
    floatx4 o[4] = { {0,0,0,0}, {0,0,0,0}, {0,0,0,0}, {0,0,0,0} };

    for (int t = 0; t < nt; ++t) {
        bool pre = (t + 1) < nt;
        float4 pfa0, pfa1, pfb0, pfb1;
        if (pre) {
            const float* xrow = x + (size_t)(b * 1024 + (t + 1) * 64 + w * 16) * 64;
            pfa0 = ((const float4*)(xrow + rl * 64 + c8a * 8))[0];
            pfa1 = ((const float4*)(xrow + rl * 64 + c8a * 8))[1];
            pfb0 = ((const float4*)(xrow + rl * 64 + c8b * 8))[0];
            pfb1 = ((const float4*)(xrow + rl * 64 + c8b * 8))[1];
        }
        __syncthreads();

        if (pre) {
            __align__(16) unsigned short ta[8] = {
                f2h(pfa0.x), f2h(pfa0.y), f2h(pfa0.z), f2h(pfa0.w),
                f2h(pfa1.x), f2h(pfa1.y), f2h(pfa1.z), f2h(pfa1.w) };
            __align__(16) unsigned short tb[8] = {
                f2h(pfb0.x), f2h(pfb0.y), f2h(pfb0.z), f2h(pfb0.w),
                f2h(pfb1.x), f2h(pfb1.y), f2h(pfb1.z), f2h(pfb1.w) };
            *(uint4*)&smem[xsl + sidx_a] = *(uint4*)ta;
            *(uint4*)&smem[xsl + sidx_b] = *(uint4*)tb;
            halfx8 kxh0 = *(const halfx8*)&smem[xsl + fidx0];
            halfx8 kxh1 = *(const halfx8*)&smem[xsl + fidx1];
            const int KLn = ((t + 1) & 1) ? KL1_OFF : KL0_OFF;
            const int VSn = ((t + 1) & 1) ? VS1_OFF : VS0_OFF;
#pragma unroll
            for (int gs = 0; gs < 4; ++gs) {
                float bbk = bk[gs * 16 + l15];
                float bbv = bv[gs * 16 + l15];
                floatx4 kacc = { bbk, bbk, bbk, bbk };
                floatx4 vacc = { bbv, bbv, bbv, bbv };
                kacc = MFMA16(kxh0, wkf0[gs], kacc);
                kacc = MFMA16(kxh1, wkf1[gs], kacc);
                vacc = MFMA16(kxh0, wvf0[gs], vacc);
                vacc = MFMA16(kxh1, wvf1[gs], vacc);
                int c8 = gs * 2 + (l15 >> 3);
                int g  = gs * 16 + l15;
#pragma unroll
                for (int r = 0; r < 4; ++r) {
                    int key = w * 16 + quad * 4 + r;
                    smem[KLn + key * 64 + ((c8 ^ (key & 7)) * 8) + (l15 & 7)] = f2h(kacc[r]);
                    smem[VSn + g * 64 + (((key >> 3) ^ (g & 7)) * 8) + (key & 7)] = f2h(vacc[r]);
                }
            }
        }

        const int KLc = (t & 1) ? KL1_OFF : KL0_OFF;
        const int VSc = (t & 1) ? VS1_OFF : VS0_OFF;

        floatx4 s[4];
#pragma unroll
        for (int sub = 0; sub < 4; ++sub) {
            int krow = sub * 16 + l15;
            halfx8 bk0 = *(const halfx8*)&smem[KLc + krow * 64 + (((0 + quad) ^ (krow & 7)) * 8)];
            halfx8 bk1 = *(const halfx8*)&smem[KLc + krow * 64 + (((4 + quad) ^ (krow & 7)) * 8)];
            floatx4 acc = { 0, 0, 0, 0 };
            acc = MFMA16(aq0, bk0, acc);
            acc = MFMA16(aq1, bk1, acc);
            s[sub] = acc;
        }
        if (t >= fullt) {
#pragma unroll
            for (int sub = 0; sub < 4; ++sub) {
                int key = t * 64 + sub * 16 + l15;
                if (key >= vl) { s[sub][0] = -1e6f; s[sub][1] = -1e6f; s[sub][2] = -1e6f; s[sub][3] = -1e6f; }
            }
        }

        float p[4][4];
        float alpha[4];
#pragma unroll
        for (int r = 0; r < 4; ++r) {
            float mx = fmaxf(fmaxf(s[0][r], s[1][r]), fmaxf(s[2][r], s[3][r]));
#pragma unroll
            for (int off = 1; off < 16; off <<= 1)
                mx = fmaxf(mx, __shfl_xor(mx, off, 64));
            float mnew = fmaxf(m_r[r], mx);
            alpha[r] = __expf(m_r[r] - mnew);
            float psum = 0.f;
#pragma unroll
            for (int sub = 0; sub < 4; ++sub) {
                float pv = __expf(s[sub][r] - mnew);
                p[sub][r] = pv;
                psum += pv;
            }
            l_lane[r] = l_lane[r] * alpha[r] + psum;
            m_r[r] = mnew;
        }
#pragma unroll
        for (int gs = 0; gs < 4; ++gs) {
            o[gs][0] *= alpha[0]; o[gs][1] *= alpha[1];
            o[gs][2] *= alpha[2]; o[gs][3] *= alpha[3];
        }

        unsigned short* psw = &smem[PS_OFF + w * 1024];
#pragma unroll
        for (int sub = 0; sub < 4; ++sub) {
            int c8 = sub * 2 + (l15 >> 3);
#pragma unroll
            for (int r = 0; r < 4; ++r) {
                int row = quad * 4 + r;
                psw[row * 64 + ((c8 ^ (row & 7)) * 8) + (l15 & 7)] = f2h(p[sub][r]);
            }
        }
        halfx8 ap0 = *(const halfx8*)&psw[fidx0];
        halfx8 ap1 = *(const halfx8*)&psw[fidx1];

#pragma unroll
        for (int gs = 0; gs < 4; ++gs) {
            int grow = gs * 16 + l15;
            halfx8 bv0 = *(const halfx8*)&smem[VSc + grow * 64 + (((0 + quad) ^ (grow & 7)) * 8)];
            halfx8 bv1 = *(const halfx8*)&smem[VSc + grow * 64 + (((4 + quad) ^ (grow & 7)) * 8)];
            o[gs] = MFMA16(ap0, bv0, o[gs]);
            o[gs] = MFMA16(ap1, bv1, o[gs]);
        }
    }

    float l[4];
#pragma unroll
    for (int r = 0; r < 4; ++r) {
        float ss = l_lane[r];
#pragma unroll
        for (int off = 1; off < 16; off <<= 1)
            ss += __shfl_xor(ss, off, 64);
        l[r] = ss;
    }
#pragma unroll
    for (int gs = 0; gs < 4; ++gs) {
#pragma unroll
        for (int r = 0; r < 4; ++r) {
            int row = row0 + w * 16 + quad * 4 + r;
            out[row * 64 + gs * 16 + l15] = o[gs][r] / l[r];
        }
    }
}

// ---------------------------------------------------------------------------
extern "C" void kernel_launch(void* const* d_in, const int* in_sizes, int n_in,
                              void* d_out, int out_size, void* d_ws, size_t ws_size,
                              hipStream_t stream) {
    const float* x    = (const float*)d_in[0];
    const int*   vlen = (const int*)  d_in[1];
    const float* Wq   = (const float*)d_in[2];
    const float* bq   = (const float*)d_in[3];
    const float* Wk   = (const float*)d_in[4];
    const float* bk   = (const float*)d_in[5];
    const float* Wv   = (const float*)d_in[6];
    const float* bv   = (const float*)d_in[7];
    float* out = (float*)d_out;

    const size_t IMG_SHORTS = (size_t)32 * 16 * 4096;         // 4 MB per image
    const size_t NEED = 3 * IMG_SHORTS * sizeof(unsigned short);  // 12 MB

    if (ws_size >= NEED) {
        unsigned short* qimg = (unsigned short*)d_ws;
        unsigned short* kimg = qimg + IMG_SHORTS;
        unsigned short* vimg = kimg + IMG_SHORTS;
        proj_kernel<<<512, 256, 0, stream>>>(x, Wq, bq, Wk, bk, Wv, bv,
                                             qimg, kimg, vimg);
        attn_kernel<<<512, 256, 0, stream>>>(qimg, kimg, vimg, vlen, out);
    } else {
        fused_attn_fallback<<<512, 256, 0, stream>>>(
            x, Wq, bq, Wk, bk, Wv, bv, vlen, out);
    }
}

// Round 3
// 99.114 us; speedup vs baseline: 1.0836x; 1.0700x over previous
//
#include <hip/hip_runtime.h>
#include <stdint.h>

// Problem constants: B=32, N=1024, C=64, G=64
//
// R18 = barrier-free pass 2.
// R17 postmortem: top-5 = fillBufferAligned ~44us (256MiB ws re-poison) ->
// ~54us of dur_us is harness floor (fill + small dispatches); R15's 107.4 =
// 52(kernel)+~55(floor). R17's 106 => proj+attn still ~= 52us: the two-pass
// moved work but the per-tile {DMA-wait + s_barrier + serial softmax} at 8
// waves/CU still serializes everything.
//   Fix: K/V images are L2-resident (131KB/batch) -> each wave reads its
//   K/V MFMA fragments DIRECTLY global->VGPR (16x 16B/lane per tile, full
//   cache-line coverage). No inter-wave sharing -> ZERO barriers in the
//   K-tile loop. K(t+1) register-prefetched after QK consumes K(t); V(t)
//   issued at tile top (~400cy ahead of PV). LDS = 8KB wave-private P
//   staging only. Arithmetic verbatim -> bit-identical.
// Fallback: if ws_size < 12MB, launch the unmodified R15 kernel.

typedef __attribute__((ext_vector_type(4))) float    floatx4;
typedef __attribute__((ext_vector_type(8))) _Float16 halfx8;

static __device__ __forceinline__ unsigned short f2h(float f) {
    union { _Float16 h; unsigned short u; } v; v.h = (_Float16)f;
    return v.u;
}
static __device__ __forceinline__ float h2f(unsigned short u) {
    union { unsigned short u; _Float16 h; } v; v.u = u;
    return (float)v.h;
}

#define MFMA16(a, bb, c) __builtin_amdgcn_mfma_f32_16x16x32_f16((a), (bb), (c), 0, 0, 0)

// ============================================================================
// Pass 1: projections (verbatim R17). Block blk = b*16 + tile handles x rows
// blk*64..blk*64+63; writes three 8KB pre-swizzled fp16 images per block:
//   Q/K image: img[row*64 + ((c8 ^ (row&7))*8) + j] = P[row][c8*8+j]
//   V image  : img[g*64  + ((kc8 ^ (g&7))*8) + j]   = V[kc8*8+j][g]   (V^T)
// ============================================================================
__global__ __launch_bounds__(256, 2) void proj_kernel(
    const float* __restrict__ x,
    const float* __restrict__ Wq, const float* __restrict__ bq,
    const float* __restrict__ Wk, const float* __restrict__ bk,
    const float* __restrict__ Wv, const float* __restrict__ bv,
    unsigned short* __restrict__ qimg,
    unsigned short* __restrict__ kimg,
    unsigned short* __restrict__ vimg)
{
    __shared__ __align__(16) unsigned short sm[24576];   // 48 KB
    const int XH = 0, XL = 4096, WQH = 8192, WQL = 12288, WKH = 16384, WVH = 20480;

    const int tid  = threadIdx.x;
    const int blk  = blockIdx.x;          // 0..511
    const int lane = tid & 63;
    const int w    = tid >> 6;
    const int l15  = lane & 15;
    const int quad = lane >> 4;
    const int rl   = lane >> 2;
    const int c8a  = 2 * (lane & 3);
    const int c8b  = c8a + 1;
    const int sidx_a = rl * 64 + ((c8a ^ (rl & 7)) * 8);
    const int sidx_b = rl * 64 + ((c8b ^ (rl & 7)) * 8);

    // ---- stage x (hi + lo residual), wave-private 16-row slices ----
    {
        const float* xrow = x + (size_t)(blk * 64 + w * 16) * 64;
#pragma unroll
        for (int i = 0; i < 2; ++i) {
            int c8   = (i == 0) ? c8a : c8b;
            int sidx = (i == 0) ? sidx_a : sidx_b;
            const float4* gp = (const float4*)(xrow + rl * 64 + c8 * 8);
            float4 f0 = gp[0], f1 = gp[1];
            float fv[8] = { f0.x, f0.y, f0.z, f0.w, f1.x, f1.y, f1.z, f1.w };
            __align__(16) unsigned short thi[8], tlo[8];
#pragma unroll
            for (int j = 0; j < 8; ++j) {
                unsigned short hi = f2h(fv[j]);
                thi[j] = hi;
                tlo[j] = f2h(fv[j] - h2f(hi));
            }
            *(uint4*)&sm[XH + w * 1024 + sidx] = *(uint4*)thi;
            *(uint4*)&sm[XL + w * 1024 + sidx] = *(uint4*)tlo;
        }
    }
    // ---- stage Wq(hi,lo), Wk, Wv  ([g][c] transposed, XOR-swizzled) ----
    {
        int g = tid & 63, ci = tid >> 6;
#pragma unroll
        for (int j = 0; j < 16; ++j) {
            int c = ci * 16 + j;
            int idx = g * 64 + (((c >> 3) ^ (g & 7)) * 8) + (c & 7);
            float fq = Wq[c * 64 + g];
            unsigned short qhi = f2h(fq);
            sm[WQH + idx] = qhi;
            sm[WQL + idx] = f2h(fq - h2f(qhi));
            sm[WKH + idx] = f2h(Wk[c * 64 + g]);
            sm[WVH + idx] = f2h(Wv[c * 64 + g]);
        }
    }
    __syncthreads();

    const int fidx0 = l15 * 64 + (((0 + quad) ^ (l15 & 7)) * 8);
    const int fidx1 = l15 * 64 + (((4 + quad) ^ (l15 & 7)) * 8);
    halfx8 ah0 = *(const halfx8*)&sm[XH + w * 1024 + fidx0];
    halfx8 ah1 = *(const halfx8*)&sm[XH + w * 1024 + fidx1];
    halfx8 al0 = *(const halfx8*)&sm[XL + w * 1024 + fidx0];
    halfx8 al1 = *(const halfx8*)&sm[XL + w * 1024 + fidx1];

    floatx4 vacc[4];
#pragma unroll
    for (int gs = 0; gs < 4; ++gs) {
        int brow = gs * 16 + l15;
        int b0 = brow * 64 + (((0 + quad) ^ (brow & 7)) * 8);
        int b1 = brow * 64 + (((4 + quad) ^ (brow & 7)) * 8);
        halfx8 bh0 = *(const halfx8*)&sm[WQH + b0];
        halfx8 bh1 = *(const halfx8*)&sm[WQH + b1];
        halfx8 bl0 = *(const halfx8*)&sm[WQL + b0];
        halfx8 bl1 = *(const halfx8*)&sm[WQL + b1];
        halfx8 wk0 = *(const halfx8*)&sm[WKH + b0];
        halfx8 wk1 = *(const halfx8*)&sm[WKH + b1];
        halfx8 wv0 = *(const halfx8*)&sm[WVH + b0];
        halfx8 wv1 = *(const halfx8*)&sm[WVH + b1];

        float bbq = bq[gs * 16 + l15];
        floatx4 qa = { bbq, bbq, bbq, bbq };
        qa = MFMA16(ah0, bh0, qa);
        qa = MFMA16(ah1, bh1, qa);
        qa = MFMA16(ah0, bl0, qa);
        qa = MFMA16(ah1, bl1, qa);
        qa = MFMA16(al0, bh0, qa);
        qa = MFMA16(al1, bh1, qa);

        float bbk = bk[gs * 16 + l15];
        float bbv = bv[gs * 16 + l15];
        floatx4 ka = { bbk, bbk, bbk, bbk };
        floatx4 va = { bbv, bbv, bbv, bbv };
        ka = MFMA16(ah0, wk0, ka);
        ka = MFMA16(ah1, wk1, ka);
        va = MFMA16(ah0, wv0, va);
        va = MFMA16(ah1, wv1, va);
        vacc[gs] = va;

        // Q image -> XH (own-wave rows), K image -> XL (own-wave rows).
        int c8 = gs * 2 + (l15 >> 3);
#pragma unroll
        for (int r = 0; r < 4; ++r) {
            int row = w * 16 + quad * 4 + r;
            int idx = row * 64 + ((c8 ^ (row & 7)) * 8) + (l15 & 7);
            sm[XH + idx] = f2h(qa[r]);
            sm[XL + idx] = f2h(ka[r]);
        }
    }
    __syncthreads();   // all waves done reading Wq-hi -> WQH reusable as V image
#pragma unroll
    for (int gs = 0; gs < 4; ++gs) {
        int g = gs * 16 + l15;
#pragma unroll
        for (int r = 0; r < 4; ++r) {
            int key = w * 16 + quad * 4 + r;
            sm[WQH + g * 64 + (((key >> 3) ^ (g & 7)) * 8) + (key & 7)] = f2h(vacc[gs][r]);
        }
    }
    __syncthreads();

    // ---- cooperative copy: 3 x 8KB images -> global workspace ----
    {
        const size_t tb = (size_t)blk * 4096;   // shorts per image
#pragma unroll
        for (int i = 0; i < 2; ++i) {
            int ci = i * 256 + tid;             // 512 x 16B chunks per image
            *(uint4*)&qimg[tb + ci * 8] = *(const uint4*)&sm[XH  + ci * 8];
            *(uint4*)&kimg[tb + ci * 8] = *(const uint4*)&sm[XL  + ci * 8];
            *(uint4*)&vimg[tb + ci * 8] = *(const uint4*)&sm[WQH + ci * 8];
        }
    }
}

// ============================================================================
// Pass 2: barrier-free attention. Each wave owns 16 q-rows; K/V fragments
// read directly global->VGPR from the L2-resident images. No LDS K/V, no
// per-tile barriers. LDS = per-wave P staging (8 KB) + sched.
// ============================================================================
__global__ __launch_bounds__(256, 2) void attn_kernel(
    const unsigned short* __restrict__ qimg,
    const unsigned short* __restrict__ kimg,
    const unsigned short* __restrict__ vimg,
    const int* __restrict__ valid_len, float* __restrict__ out)
{
    __shared__ __align__(16) unsigned short psmem[4096];  // 8 KB: 4 waves x 2KB
    __shared__ int sched[32];

    const int tid  = threadIdx.x;
    const int blk  = blockIdx.x;          // 0..511
    const int lane = tid & 63;
    const int w    = tid >> 6;
    const int l15  = lane & 15;
    const int quad = lane >> 4;

    // ---------- device-side balanced schedule (identical in every block) ----
    if (tid < 32) {
        int vlb = valid_len[tid];
        int ntb = (vlb == 0) ? 16 : ((vlb + 63) >> 6);
        int rank = 0;
        for (int b2 = 0; b2 < 32; ++b2) {
            int vl2 = valid_len[b2];
            int nt2 = (vl2 == 0) ? 16 : ((vl2 + 63) >> 6);
            rank += (nt2 > ntb) || (nt2 == ntb && b2 < tid);
        }
        sched[rank] = tid;
    }
    __syncthreads();   // the ONLY block-wide barrier

    const int b    = (blk < 256) ? sched[blk >> 4] : sched[31 - ((blk - 256) >> 4)];
    const int qt   = blk & 15;
    const int row0 = b * 1024 + qt * 64;

    const int vl    = valid_len[b];
    const int nt    = (vl == 0) ? 16 : ((vl + 63) >> 6);
    const int fullt = vl >> 6;

    // ---- Q fragments straight from the global image ----
    const int arow = w * 16 + l15;
    const unsigned short* qb = qimg + (size_t)(b * 16 + qt) * 4096;
    halfx8 aq0 = *(const halfx8*)&qb[arow * 64 + (((0 + quad) ^ (arow & 7)) * 8)];
    halfx8 aq1 = *(const halfx8*)&qb[arow * 64 + (((4 + quad) ^ (arow & 7)) * 8)];

    // ---- fragment byte indices within a 4096-short tile image ----
    // K row (key) and V row (g) use the same formula: r = sub*16 + l15.
    int idx0[4], idx1[4];
#pragma unroll
    for (int sub = 0; sub < 4; ++sub) {
        int r = sub * 16 + l15;
        idx0[sub] = r * 64 + (((0 + quad) ^ (r & 7)) * 8);
        idx1[sub] = r * 64 + (((4 + quad) ^ (r & 7)) * 8);
    }

    const unsigned short* kt_base = kimg + (size_t)b * 65536;
    const unsigned short* vt_base = vimg + (size_t)b * 65536;

    float m_r[4]    = { -INFINITY, -INFINITY, -INFINITY, -INFINITY };
    float l_lane[4] = { 0.f, 0.f, 0.f, 0.f };
    floatx4 o[4] = { {0,0,0,0}, {0,0,0,0}, {0,0,0,0}, {0,0,0,0} };

    unsigned short* psw = &psmem[w * 1024];

    // preload K(0)
    halfx8 kf0[4], kf1[4];
#pragma unroll
    for (int sub = 0; sub < 4; ++sub) {
        kf0[sub] = *(const halfx8*)&kt_base[idx0[sub]];
        kf1[sub] = *(const halfx8*)&kt_base[idx1[sub]];
    }

    for (int t = 0; t < nt; ++t) {
        // issue V(t) loads now; first use is after softmax (~400 cy cover)
        const unsigned short* vt = vt_base + (size_t)t * 4096;
        halfx8 vf0[4], vf1[4];
#pragma unroll
        for (int sub = 0; sub < 4; ++sub) {
            vf0[sub] = *(const halfx8*)&vt[idx0[sub]];
            vf1[sub] = *(const halfx8*)&vt[idx1[sub]];
        }

        // ---- scores (consume K(t)) ----
        floatx4 s[4];
#pragma unroll
        for (int sub = 0; sub < 4; ++sub) {
            floatx4 acc = { 0, 0, 0, 0 };
            acc = MFMA16(aq0, kf0[sub], acc);
            acc = MFMA16(aq1, kf1[sub], acc);
            s[sub] = acc;
        }

        // K(t) consumed -> issue K(t+1) prefetch (covered by softmax+PV)
        const bool pre = (t + 1) < nt;
        halfx8 nk0[4], nk1[4];
        if (pre) {
            const unsigned short* ktn = kt_base + (size_t)(t + 1) * 4096;
#pragma unroll
            for (int sub = 0; sub < 4; ++sub) {
                nk0[sub] = *(const halfx8*)&ktn[idx0[sub]];
                nk1[sub] = *(const halfx8*)&ktn[idx1[sub]];
            }
        }

        if (t >= fullt) {
#pragma unroll
            for (int sub = 0; sub < 4; ++sub) {
                int key = t * 64 + sub * 16 + l15;
                if (key >= vl) { s[sub][0] = -1e6f; s[sub][1] = -1e6f; s[sub][2] = -1e6f; s[sub][3] = -1e6f; }
            }
        }

        // ---- online softmax (verbatim R15) ----
        float p[4][4];
        float alpha[4];
#pragma unroll
        for (int r = 0; r < 4; ++r) {
            float mx = fmaxf(fmaxf(s[0][r], s[1][r]), fmaxf(s[2][r], s[3][r]));
#pragma unroll
            for (int off = 1; off < 16; off <<= 1)
                mx = fmaxf(mx, __shfl_xor(mx, off, 64));
            float mnew = fmaxf(m_r[r], mx);
            alpha[r] = __expf(m_r[r] - mnew);
            float psum = 0.f;
#pragma unroll
            for (int sub = 0; sub < 4; ++sub) {
                float pv = __expf(s[sub][r] - mnew);
                p[sub][r] = pv;
                psum += pv;
            }
            l_lane[r] = l_lane[r] * alpha[r] + psum;
            m_r[r] = mnew;
        }
#pragma unroll
        for (int gs = 0; gs < 4; ++gs) {
            o[gs][0] *= alpha[0]; o[gs][1] *= alpha[1];
            o[gs][2] *= alpha[2]; o[gs][3] *= alpha[3];
        }

        // ---- P staging (wave-private LDS) + PV ----
#pragma unroll
        for (int sub = 0; sub < 4; ++sub) {
            int c8 = sub * 2 + (l15 >> 3);
#pragma unroll
            for (int r = 0; r < 4; ++r) {
                int row = quad * 4 + r;
                psw[row * 64 + ((c8 ^ (row & 7)) * 8) + (l15 & 7)] = f2h(p[sub][r]);
            }
        }
        halfx8 ap0 = *(const halfx8*)&psw[l15 * 64 + (((0 + quad) ^ (l15 & 7)) * 8)];
        halfx8 ap1 = *(const halfx8*)&psw[l15 * 64 + (((4 + quad) ^ (l15 & 7)) * 8)];

#pragma unroll
        for (int gs = 0; gs < 4; ++gs) {
            o[gs] = MFMA16(ap0, vf0[gs], o[gs]);
            o[gs] = MFMA16(ap1, vf1[gs], o[gs]);
        }

        if (pre) {
#pragma unroll
            for (int sub = 0; sub < 4; ++sub) {
                kf0[sub] = nk0[sub];
                kf1[sub] = nk1[sub];
            }
        }
    }

    // ---- final 16-lane sum butterfly, store ----
    float l[4];
#pragma unroll
    for (int r = 0; r < 4; ++r) {
        float ss = l_lane[r];
#pragma unroll
        for (int off = 1; off < 16; off <<= 1)
            ss += __shfl_xor(ss, off, 64);
        l[r] = ss;
    }
#pragma unroll
    for (int gs = 0; gs < 4; ++gs) {
#pragma unroll
        for (int r = 0; r < 4; ++r) {
            int row = row0 + w * 16 + quad * 4 + r;
            out[row * 64 + gs * 16 + l15] = o[gs][r] / l[r];
        }
    }
}

// ============================================================================
// Fallback: unmodified R15 single-pass kernel (used if ws_size < 12 MB)
// ============================================================================
__global__ __launch_bounds__(256, 2) void fused_attn_fallback(
    const float* __restrict__ x,
    const float* __restrict__ Wq, const float* __restrict__ bq,
    const float* __restrict__ Wk, const float* __restrict__ bk,
    const float* __restrict__ Wv, const float* __restrict__ bv,
    const int* __restrict__ valid_len, float* __restrict__ out)
{
    __shared__ __align__(16) unsigned short smem[28672];   // 56 KB
    __shared__ int sched[32];

    const int Q_OFF = 0, XH_OFF = 4096, KL0_OFF = 8192, KL1_OFF = 12288,
              VS0_OFF = 16384, VS1_OFF = 20480, PS_OFF = 24576;

    const int tid  = threadIdx.x;
    const int blk  = blockIdx.x;
    const int lane = tid & 63;
    const int w    = tid >> 6;
    const int l15  = lane & 15;
    const int quad = lane >> 4;

    if (tid < 32) {
        int vlb = valid_len[tid];
        int ntb = (vlb == 0) ? 16 : ((vlb + 63) >> 6);
        int rank = 0;
        for (int b2 = 0; b2 < 32; ++b2) {
            int vl2 = valid_len[b2];
            int nt2 = (vl2 == 0) ? 16 : ((vl2 + 63) >> 6);
            rank += (nt2 > ntb) || (nt2 == ntb && b2 < tid);
        }
        sched[rank] = tid;
    }
    __syncthreads();

    const int hv   = (blk < 256);
    const int b    = hv ? sched[blk >> 4] : sched[31 - ((blk - 256) >> 4)];
    const int n0   = (blk & 15) * 64;
    const int row0 = b * 1024 + n0;

    const int xsl  = XH_OFF + w * 1024;
    const int fidx0 = l15 * 64 + (((0 + quad) ^ (l15 & 7)) * 8);
    const int fidx1 = l15 * 64 + (((4 + quad) ^ (l15 & 7)) * 8);
    const int rl   = lane >> 2;
    const int c8a  = 2 * (lane & 3);
    const int c8b  = 2 * (lane & 3) + 1;
    const int sidx_a = rl * 64 + ((c8a ^ (rl & 7)) * 8);
    const int sidx_b = rl * 64 + ((c8b ^ (rl & 7)) * 8);

    const int vl    = valid_len[b];
    const int nt    = (vl == 0) ? 16 : ((vl + 63) >> 6);
    const int fullt = vl >> 6;

    {
        const float* xrow = x + (size_t)(row0 + w * 16) * 64;
#pragma unroll
        for (int i = 0; i < 2; ++i) {
            int c8 = (i == 0) ? c8a : c8b;
            int sidx = (i == 0) ? sidx_a : sidx_b;
            const float4* gp = (const float4*)(xrow + rl * 64 + c8 * 8);
            float4 f0 = gp[0], f1 = gp[1];
            float fv[8] = { f0.x, f0.y, f0.z, f0.w, f1.x, f1.y, f1.z, f1.w };
            __align__(16) unsigned short thi[8], tlo[8];
#pragma unroll
            for (int j = 0; j < 8; ++j) {
                unsigned short hi = f2h(fv[j]);
                thi[j] = hi;
                tlo[j] = f2h(fv[j] - h2f(hi));
            }
            *(uint4*)&smem[xsl + sidx]                = *(uint4*)thi;
            *(uint4*)&smem[VS0_OFF + w * 1024 + sidx] = *(uint4*)tlo;
        }
    }
    {
        int g = tid & 63, ci = tid >> 6;
#pragma unroll
        for (int j = 0; j < 16; ++j) {
            int c = ci * 16 + j;
            int idx = g * 64 + (((c >> 3) ^ (g & 7)) * 8) + (c & 7);
            float fq = Wq[c * 64 + g];
            unsigned short qhi = f2h(fq);
            smem[KL0_OFF + idx] = qhi;
            smem[KL1_OFF + idx] = f2h(fq - h2f(qhi));
            smem[VS1_OFF + idx] = f2h(Wk[c * 64 + g]);
            smem[PS_OFF  + idx] = f2h(Wv[c * 64 + g]);
        }
    }
    __syncthreads();

    halfx8 wkf0[4], wkf1[4], wvf0[4], wvf1[4];
#pragma unroll
    for (int gs = 0; gs < 4; ++gs) {
        int brow = gs * 16 + l15;
        int b0 = brow * 64 + (((0 + quad) ^ (brow & 7)) * 8);
        int b1 = brow * 64 + (((4 + quad) ^ (brow & 7)) * 8);
        wkf0[gs] = *(const halfx8*)&smem[VS1_OFF + b0];
        wkf1[gs] = *(const halfx8*)&smem[VS1_OFF + b1];
        wvf0[gs] = *(const halfx8*)&smem[PS_OFF + b0];
        wvf1[gs] = *(const halfx8*)&smem[PS_OFF + b1];
    }

    {
        halfx8 ah0 = *(const halfx8*)&smem[xsl + fidx0];
        halfx8 ah1 = *(const halfx8*)&smem[xsl + fidx1];
        halfx8 al0 = *(const halfx8*)&smem[VS0_OFF + w * 1024 + fidx0];
        halfx8 al1 = *(const halfx8*)&smem[VS0_OFF + w * 1024 + fidx1];
#pragma unroll
        for (int gs = 0; gs < 4; ++gs) {
            int brow = gs * 16 + l15;
            float bb = bq[gs * 16 + l15];
            floatx4 acc = { bb, bb, bb, bb };
            int b0 = brow * 64 + (((0 + quad) ^ (brow & 7)) * 8);
            int b1 = brow * 64 + (((4 + quad) ^ (brow & 7)) * 8);
            halfx8 bh0 = *(const halfx8*)&smem[KL0_OFF + b0];
            halfx8 bh1 = *(const halfx8*)&smem[KL0_OFF + b1];
            halfx8 bl0 = *(const halfx8*)&smem[KL1_OFF + b0];
            halfx8 bl1 = *(const halfx8*)&smem[KL1_OFF + b1];
            acc = MFMA16(ah0, bh0, acc);
            acc = MFMA16(ah1, bh1, acc);
            acc = MFMA16(ah0, bl0, acc);
            acc = MFMA16(ah1, bl1, acc);
            acc = MFMA16(al0, bh0, acc);
            acc = MFMA16(al1, bh1, acc);
            int c8 = gs * 2 + (l15 >> 3);
#pragma unroll
            for (int r = 0; r < 4; ++r) {
                int row = w * 16 + quad * 4 + r;
                smem[Q_OFF + row * 64 + ((c8 ^ (row & 7)) * 8) + (l15 & 7)] = f2h(acc[r]);
            }
        }
    }
    const int arow = w * 16 + l15;
    halfx8 aq0 = *(const halfx8*)&smem[Q_OFF + arow * 64 + (((0 + quad) ^ (arow & 7)) * 8)];
    halfx8 aq1 = *(const halfx8*)&smem[Q_OFF + arow * 64 + (((4 + quad) ^ (arow & 7)) * 8)];

    {
        const float* xrow = x + (size_t)(b * 1024 + w * 16) * 64;
#pragma unroll
        for (int i = 0; i < 2; ++i) {
            int c8 = (i == 0) ? c8a : c8b;
            int sidx = (i == 0) ? sidx_a : sidx_b;
            const float4* gp = (const float4*)(xrow + rl * 64 + c8 * 8);
            float4 f0 = gp[0], f1 = gp[1];
            __align__(16) unsigned short thi[8] = {
                f2h(f0.x), f2h(f0.y), f2h(f0.z), f2h(f0.w),
                f2h(f1.x), f2h(f1.y), f2h(f1.z), f2h(f1.w) };
            *(uint4*)&smem[xsl + sidx] = *(uint4*)thi;
        }
    }
    __syncthreads();

    {
        halfx8 kxh0 = *(const halfx8*)&smem[xsl + fidx0];
        halfx8 kxh1 = *(const halfx8*)&smem[xsl + fidx1];
#pragma unroll
        for (int gs = 0; gs < 4; ++gs) {
            float bbk = bk[gs * 16 + l15];
            float bbv = bv[gs * 16 + l15];
            floatx4 kacc = { bbk, bbk, bbk, bbk };
            floatx4 vacc = { bbv, bbv, bbv, bbv };
            kacc = MFMA16(kxh0, wkf0[gs], kacc);
            kacc = MFMA16(kxh1, wkf1[gs], kacc);
            vacc = MFMA16(kxh0, wvf0[gs], vacc);
            vacc = MFMA16(kxh1, wvf1[gs], vacc);
            int c8 = gs * 2 + (l15 >> 3);
            int g  = gs * 16 + l15;
#pragma unroll
            for (int r = 0; r < 4; ++r) {
                int key = w * 16 + quad * 4 + r;
                smem[KL0_OFF + key * 64 + ((c8 ^ (key & 7)) * 8) + (l15 & 7)] = f2h(kacc[r]);
                smem[VS0_OFF + g * 64 + (((key >> 3) ^ (g & 7)) * 8) + (key & 7)] = f2h(vacc[r]);
            }
        }
    }

    float m_r[4]    = { -INFINITY, -INFINITY, -INFINITY, -INFINITY };
    float l_lane[4] = { 0.f, 0.f, 0.f, 0.f };
    floatx4 o[4] = { {0,0,0,0}, {0,0,0,0}, {0,0,0,0}, {0,0,0,0} };

    for (int t = 0; t < nt; ++t) {
        bool pre = (t + 1) < nt;
        float4 pfa0, pfa1, pfb0, pfb1;
        if (pre) {
            const float* xrow = x + (size_t)(b * 1024 + (t + 1) * 64 + w * 16) * 64;
            pfa0 = ((const float4*)(xrow + rl * 64 + c8a * 8))[0];
            pfa1 = ((const float4*)(xrow + rl * 64 + c8a * 8))[1];
            pfb0 = ((const float4*)(xrow + rl * 64 + c8b * 8))[0];
            pfb1 = ((const float4*)(xrow + rl * 64 + c8b * 8))[1];
        }
        __syncthreads();

        if (pre) {
            __align__(16) unsigned short ta[8] = {
                f2h(pfa0.x), f2h(pfa0.y), f2h(pfa0.z), f2h(pfa0.w),
                f2h(pfa1.x), f2h(pfa1.y), f2h(pfa1.z), f2h(pfa1.w) };
            __align__(16) unsigned short tb[8] = {
                f2h(pfb0.x), f2h(pfb0.y), f2h(pfb0.z), f2h(pfb0.w),
                f2h(pfb1.x), f2h(pfb1.y), f2h(pfb1.z), f2h(pfb1.w) };
            *(uint4*)&smem[xsl + sidx_a] = *(uint4*)ta;
            *(uint4*)&smem[xsl + sidx_b] = *(uint4*)tb;
            halfx8 kxh0 = *(const halfx8*)&smem[xsl + fidx0];
            halfx8 kxh1 = *(const halfx8*)&smem[xsl + fidx1];
            const int KLn = ((t + 1) & 1) ? KL1_OFF : KL0_OFF;
            const int VSn = ((t + 1) & 1) ? VS1_OFF : VS0_OFF;
#pragma unroll
            for (int gs = 0; gs < 4; ++gs) {
                float bbk = bk[gs * 16 + l15];
                float bbv = bv[gs * 16 + l15];
                floatx4 kacc = { bbk, bbk, bbk, bbk };
                floatx4 vacc = { bbv, bbv, bbv, bbv };
                kacc = MFMA16(kxh0, wkf0[gs], kacc);
                kacc = MFMA16(kxh1, wkf1[gs], kacc);
                vacc = MFMA16(kxh0, wvf0[gs], vacc);
                vacc = MFMA16(kxh1, wvf1[gs], vacc);
                int c8 = gs * 2 + (l15 >> 3);
                int g  = gs * 16 + l15;
#pragma unroll
                for (int r = 0; r < 4; ++r) {
                    int key = w * 16 + quad * 4 + r;
                    smem[KLn + key * 64 + ((c8 ^ (key & 7)) * 8) + (l15 & 7)] = f2h(kacc[r]);
                    smem[VSn + g * 64 + (((key >> 3) ^ (g & 7)) * 8) + (key & 7)] = f2h(vacc[r]);
                }
            }
        }

        const int KLc = (t & 1) ? KL1_OFF : KL0_OFF;
        const int VSc = (t & 1) ? VS1_OFF : VS0_OFF;

        floatx4 s[4];
#pragma unroll
        for (int sub = 0; sub < 4; ++sub) {
            int krow = sub * 16 + l15;
            halfx8 bk0 = *(const halfx8*)&smem[KLc + krow * 64 + (((0 + quad) ^ (krow & 7)) * 8)];
            halfx8 bk1 = *(const halfx8*)&smem[KLc + krow * 64 + (((4 + quad) ^ (krow & 7)) * 8)];
            floatx4 acc = { 0, 0, 0, 0 };
            acc = MFMA16(aq0, bk0, acc);
            acc = MFMA16(aq1, bk1, acc);
            s[sub] = acc;
        }
        if (t >= fullt) {
#pragma unroll
            for (int sub = 0; sub < 4; ++sub) {
                int key = t * 64 + sub * 16 + l15;
                if (key >= vl) { s[sub][0] = -1e6f; s[sub][1] = -1e6f; s[sub][2] = -1e6f; s[sub][3] = -1e6f; }
            }
        }

        float p[4][4];
        float alpha[4];
#pragma unroll
        for (int r = 0; r < 4; ++r) {
            float mx = fmaxf(fmaxf(s[0][r], s[1][r]), fmaxf(s[2][r], s[3][r]));
#pragma unroll
            for (int off = 1; off < 16; off <<= 1)
                mx = fmaxf(mx, __shfl_xor(mx, off, 64));
            float mnew = fmaxf(m_r[r], mx);
            alpha[r] = __expf(m_r[r] - mnew);
            float psum = 0.f;
#pragma unroll
            for (int sub = 0; sub < 4; ++sub) {
                float pv = __expf(s[sub][r] - mnew);
                p[sub][r] = pv;
                psum += pv;
            }
            l_lane[r] = l_lane[r] * alpha[r] + psum;
            m_r[r] = mnew;
        }
#pragma unroll
        for (int gs = 0; gs < 4; ++gs) {
            o[gs][0] *= alpha[0]; o[gs][1] *= alpha[1];
            o[gs][2] *= alpha[2]; o[gs][3] *= alpha[3];
        }

        unsigned short* psw = &smem[PS_OFF + w * 1024];
#pragma unroll
        for (int sub = 0; sub < 4; ++sub) {
            int c8 = sub * 2 + (l15 >> 3);
#pragma unroll
            for (int r = 0; r < 4; ++r) {
                int row = quad * 4 + r;
                psw[row * 64 + ((c8 ^ (row & 7)) * 8) + (l15 & 7)] = f2h(p[sub][r]);
            }
        }
        halfx8 ap0 = *(const halfx8*)&psw[fidx0];
        halfx8 ap1 = *(const halfx8*)&psw[fidx1];

#pragma unroll
        for (int gs = 0; gs < 4; ++gs) {
            int grow = gs * 16 + l15;
            halfx8 bv0 = *(const halfx8*)&smem[VSc + grow * 64 + (((0 + quad) ^ (grow & 7)) * 8)];
            halfx8 bv1 = *(const halfx8*)&smem[VSc + grow * 64 + (((4 + quad) ^ (grow & 7)) * 8)];
            o[gs] = MFMA16(ap0, bv0, o[gs]);
            o[gs] = MFMA16(ap1, bv1, o[gs]);
        }
    }

    float l[4];
#pragma unroll
    for (int r = 0; r < 4; ++r) {
        float ss = l_lane[r];
#pragma unroll
        for (int off = 1; off < 16; off <<= 1)
            ss += __shfl_xor(ss, off, 64);
        l[r] = ss;
    }
#pragma unroll
    for (int gs = 0; gs < 4; ++gs) {
#pragma unroll
        for (int r = 0; r < 4; ++r) {
            int row = row0 + w * 16 + quad * 4 + r;
            out[row * 64 + gs * 16 + l15] = o[gs][r] / l[r];
        }
    }
}

// ---------------------------------------------------------------------------
extern "C" void kernel_launch(void* const* d_in, const int* in_sizes, int n_in,
                              void* d_out, int out_size, void* d_ws, size_t ws_size,
                              hipStream_t stream) {
    const float* x    = (const float*)d_in[0];
    const int*   vlen = (const int*)  d_in[1];
    const float* Wq   = (const float*)d_in[2];
    const float* bq   = (const float*)d_in[3];
    const float* Wk   = (const float*)d_in[4];
    const float* bk   = (const float*)d_in[5];
    const float* Wv   = (const float*)d_in[6];
    const float* bv   = (const float*)d_in[7];
    float* out = (float*)d_out;

    const size_t IMG_SHORTS = (size_t)32 * 16 * 4096;         // 4 MB per image
    const size_t NEED = 3 * IMG_SHORTS * sizeof(unsigned short);  // 12 MB

    if (ws_size >= NEED) {
        unsigned short* qimg = (unsigned short*)d_ws;
        unsigned short* kimg = qimg + IMG_SHORTS;
        unsigned short* vimg = kimg + IMG_SHORTS;
        proj_kernel<<<512, 256, 0, stream>>>(x, Wq, bq, Wk, bk, Wv, bv,
                                             qimg, kimg, vimg);
        attn_kernel<<<512, 256, 0, stream>>>(qimg, kimg, vimg, vlen, out);
    } else {
        fused_attn_fallback<<<512, 256, 0, stream>>>(
            x, Wq, bq, Wk, bk, Wv, bv, vlen, out);
    }
}